// Round 17
// baseline (33.793 us; speedup 1.0000x reference)
//
#include <hip/hip_runtime.h>
#include <math.h>

#define B_ 4
#define N_ 32768
#define M_ 8192
#define K_ 16
#define D_ 64
#define O_ 64

typedef __attribute__((ext_vector_type(8))) short bf16x8;
typedef __attribute__((ext_vector_type(4))) float f32x4;

// float -> bf16 bits, round-to-nearest-even (inputs are finite normals)
static __device__ __forceinline__ short f2bf(float f) {
    unsigned u = __float_as_uint(f);
    u += 0x7fffu + ((u >> 16) & 1u);
    return (short)(u >> 16);
}

static __device__ __forceinline__ bf16x8 cvt_bf8(float4 f0, float4 f1) {
    bf16x8 v;
    v[0] = f2bf(f0.x); v[1] = f2bf(f0.y); v[2] = f2bf(f0.z); v[3] = f2bf(f0.w);
    v[4] = f2bf(f1.x); v[5] = f2bf(f1.y); v[6] = f2bf(f1.z); v[7] = f2bf(f1.w);
    return v;
}

// 8 consecutive floats -> bf16x8 (one MFMA k-chunk)
static __device__ __forceinline__ bf16x8 ld_bf8(const float* p) {
    return cvt_bf8(*(const float4*)p, *(const float4*)(p + 4));
}

#define PIN4I(q) asm volatile("" :: "v"((q).x), "v"((q).y), "v"((q).z), "v"((q).w))

// ---------------------------------------------------------------------------
// Kernel P (batch-affine): x (fp32) -> xb (bf16). Block -> XCD pair {2b,2b+1}
// writes batch b, so xb's dirty lines land in the SAME XCD pair's L2s that
// the fused kernel (same swizzle) gathers from — per-XCD L2s are not
// cross-coherent, so producer/consumer XCD alignment is what makes the
// 4.2 MB/batch working set L2-resident. 2048 blocks, 2 iters each.
// ---------------------------------------------------------------------------
__global__ __launch_bounds__(256)
void cvt_x(const float* __restrict__ x, short* __restrict__ xb) {
    const int blk  = blockIdx.x;            // 0..2047
    const int xcd  = blk & 7;
    const int slot = blk >> 3;              // 0..255
    const int bb   = xcd >> 1;
    const int half = xcd & 1;
    // batch bb elems: N_*64 = 2,097,152; per block: /512 = 4096 elems
    const size_t base = (size_t)bb * N_ * 64 + ((size_t)(half * 256 + slot)) * 4096;
    #pragma unroll
    for (int i = 0; i < 2; ++i) {
        size_t off = base + ((size_t)threadIdx.x + i * 256) * 8;
        float4 f0 = *(const float4*)(x + off);
        float4 f1 = *(const float4*)(x + off + 4);
        *(bf16x8*)(xb + off) = cvt_bf8(f0, f1);
    }
}

// ---------------------------------------------------------------------------
// Fused kernel (R17 = bf16 gathers x 8-wave TLP x L2-affinity):
//   out[b,o,m] = relu( max_k (x[b,idx[m,k]].W1[o]) + xs[b,m].(W2-W1)[o] + b[o] )
// R16 showed 512-block fused is latency-bound regardless of bytes; R15's
// 8-wave shell had fp32's 4-loads+cvt per m. This combines: wave = 4 m,
// 2 bf16 loads/m (32B in regs), all 8 issued+pinned up front, 8192 waves
// (4/SIMD), W frags via LDS, deferred shfl reductions, batch-affine swizzle
// matching cvt_x so gathers hit the local-XCD L2 (~200cy, hideable).
// ---------------------------------------------------------------------------
__global__ __launch_bounds__(512, 4)
void fused_gconv(const short* __restrict__ xb, const float* __restrict__ xs,
                 const int* __restrict__ idx, const float* __restrict__ W,
                 const float* __restrict__ bias, float* __restrict__ out) {
    __shared__ int    ldsI[512];             // 32 m x 16 k
    __shared__ bf16x8 ldsW[4][2][2][64];     // 16 KB: [t][s][b1/bd][lane]
    __shared__ float  ldsB[64];
    __shared__ float  ldsT[64 * 33];         // [o][m] transpose

    const int tid  = threadIdx.x;
    const int blk  = blockIdx.x;       // 0..1023
    const int xcd  = blk & 7;
    const int slot = blk >> 3;         // 0..127
    const int bb   = xcd >> 1;         // batch on XCD pair {2c,2c+1}
    const int m0   = (((xcd & 1) << 7) + slot) << 5;   // batch-local m base

    // stage idx: 2KB, fully coalesced
    ldsI[tid] = idx[((size_t)bb * M_ + m0) * 16 + tid];

    const int l  = tid & 63;
    const int wv = tid >> 6;           // 0..7; m-group = wv*4..wv*4+3
    const int lr = l & 15;
    const int kg = l >> 4;

    // ---- W-frag stage: wave wv converts slice t = wv>>1, s = wv&1
    {
        const int t = wv >> 1, s = wv & 1;
        const float* wp = W + (size_t)(t * 16 + lr) * 128 + s * 32 + kg * 8;
        float4 f0 = *(const float4*)wp;
        float4 f1 = *(const float4*)(wp + 4);
        float4 g0 = *(const float4*)(wp + 64);
        float4 g1 = *(const float4*)(wp + 68);
        ldsW[t][s][0][l] = cvt_bf8(f0, f1);
        float4 d0 = make_float4(g0.x - f0.x, g0.y - f0.y, g0.z - f0.z, g0.w - f0.w);
        float4 d1 = make_float4(g1.x - f1.x, g1.y - f1.y, g1.z - f1.z, g1.w - f1.w);
        ldsW[t][s][1][l] = cvt_bf8(d0, d1);
        if (tid < 64) ldsB[tid] = bias[tid];
    }
    __syncthreads();

    // ---- hoist this wave's 4 idx rows; issue ALL 8 gather loads, pin them
    int rr[4];
    #pragma unroll
    for (int j = 0; j < 4; ++j)
        rr[j] = ldsI[(wv * 4 + j) * 16 + lr];

    const short* xbb = xb + (size_t)bb * N_ * 64;
    int4 g0[4], g1[4];                 // 32 VGPRs of in-flight gather data
    #pragma unroll
    for (int j = 0; j < 4; ++j) {
        const short* xp = xbb + (size_t)(unsigned)rr[j] * 64 + kg * 8;
        g0[j] = *(const int4*)xp;          // bf16 elems kg*8 .. +8
        g1[j] = *(const int4*)(xp + 32);   // bf16 elems 32+kg*8 .. +8
    }
    #pragma unroll
    for (int j = 0; j < 4; ++j) { PIN4I(g0[j]); PIN4I(g1[j]); }

    float binit[4];
    #pragma unroll
    for (int t = 0; t < 4; ++t) binit[t] = ldsB[t * 16 + lr];

    // ---- center: block-tile (wv>>2)'s 16 xs rows vs (W2-W1), bias-init.
    // D rows kg*4+r; owner lanes kg == (wv&3) hold this wave's m = wv*4+r.
    // Runs while gathers are in flight.
    const float* xsp = xs + ((size_t)bb * M_ + m0 + (wv >> 2) * 16 + lr) * 64 + kg * 8;
    bf16x8 axs0 = ld_bf8(xsp);
    bf16x8 axs1 = ld_bf8(xsp + 32);

    float vout[4][4];                  // [t][r]
    #pragma unroll
    for (int t = 0; t < 4; ++t) {
        bf16x8 bd0 = ldsW[t][0][1][l];
        bf16x8 bd1 = ldsW[t][1][1][l];
        f32x4 a = {binit[t], binit[t], binit[t], binit[t]};
        a = __builtin_amdgcn_mfma_f32_16x16x32_bf16(axs0, bd0, a, 0, 0, 0);
        a = __builtin_amdgcn_mfma_f32_16x16x32_bf16(axs1, bd1, a, 0, 0, 0);
        vout[t][0] = a[0]; vout[t][1] = a[1];
        vout[t][2] = a[2]; vout[t][3] = a[3];
    }

    // ---- MFMA block: gathered 16B chunks ARE A-frag k-chunks (no cvt)
    float pv[4][4];                    // [t][j] in-lane partial max
    #pragma unroll
    for (int t = 0; t < 4; ++t) {
        bf16x8 w0 = ldsW[t][0][0][l];
        bf16x8 w1 = ldsW[t][1][0][l];
        #pragma unroll
        for (int j = 0; j < 4; ++j) {
            bf16x8 a0 = *(bf16x8*)&g0[j];
            bf16x8 a1 = *(bf16x8*)&g1[j];
            f32x4 a = {0.f, 0.f, 0.f, 0.f};
            a = __builtin_amdgcn_mfma_f32_16x16x32_bf16(a0, w0, a, 0, 0, 0);
            a = __builtin_amdgcn_mfma_f32_16x16x32_bf16(a1, w1, a, 0, 0, 0);
            pv[t][j] = fmaxf(fmaxf(a[0], a[1]), fmaxf(a[2], a[3]));
        }
    }

    // ---- deferred cross-lane max (nothing downstream but the adds)
    #pragma unroll
    for (int t = 0; t < 4; ++t)
        #pragma unroll
        for (int j = 0; j < 4; ++j) {
            float v = pv[t][j];
            v = fmaxf(v, __shfl_xor(v, 16));
            v = fmaxf(v, __shfl_xor(v, 32));
            if (kg == (wv & 3))        // owner lane-group
                vout[t][j] += v;
        }

    // relu + transpose write (owner lanes): [o = t*16+lr][m = wv*4 + r]
    if (kg == (wv & 3)) {
        #pragma unroll
        for (int t = 0; t < 4; ++t)
            #pragma unroll
            for (int r = 0; r < 4; ++r) {
                float v = vout[t][r];
                ldsT[(t * 16 + lr) * 33 + wv * 4 + r] = v > 0.f ? v : 0.f;
            }
    }
    __syncthreads();

    // coalesced stores: thread tid -> o = tid>>3, 4 m at (tid&7)*4
    const int o  = tid >> 3;
    const int ms = (tid & 7) * 4;
    const float* lp = &ldsT[o * 33 + ms];
    float4 v = make_float4(lp[0], lp[1], lp[2], lp[3]);
    *(float4*)(out + ((size_t)bb * 64 + o) * M_ + m0 + ms) = v;
}

// ---------------------------------------------------------------------------
// Naive exact fallback (only if ws too small for the bf16 x-copy).
// ---------------------------------------------------------------------------
__global__ void naive_all(const float* __restrict__ x, const float* __restrict__ xs,
                          const int* __restrict__ idx, const float* __restrict__ W,
                          const float* __restrict__ bias, float* __restrict__ out) {
    size_t t = (size_t)blockIdx.x * 256 + threadIdx.x;
    if (t >= (size_t)B_ * O_ * M_) return;
    int m = (int)(t % M_);
    int o = (int)((t / M_) % O_);
    int b = (int)(t / ((size_t)M_ * O_));
    const float* xp = x + (size_t)b * N_ * D_;
    const float* c  = xs + ((size_t)b * M_ + m) * D_;
    const int*   id = idx + ((size_t)b * M_ + m) * K_;
    const float* w1 = W + o * 128;
    const float* w2 = w1 + 64;
    float best = -INFINITY;
    for (int k = 0; k < K_; ++k) {
        const float* g = xp + (size_t)id[k] * D_;
        float s = bias[o];
        for (int d = 0; d < D_; ++d)
            s += (g[d] - c[d]) * w1[d] + c[d] * w2[d];
        best = fmaxf(best, s);
    }
    out[t] = best > 0.0f ? best : 0.0f;
}

extern "C" void kernel_launch(void* const* d_in, const int* in_sizes, int n_in,
                              void* d_out, int out_size, void* d_ws, size_t ws_size,
                              hipStream_t stream) {
    const float* x    = (const float*)d_in[0];
    const float* xs   = (const float*)d_in[1];
    const int*   idx  = (const int*)d_in[2];
    const float* W    = (const float*)d_in[3];
    const float* bias = (const float*)d_in[4];
    float* out = (float*)d_out;

    const size_t needXB = (size_t)B_ * N_ * 64 * sizeof(short);  // 16.78 MB
    if (ws_size < needXB) {
        size_t total = (size_t)B_ * O_ * M_;
        naive_all<<<(int)((total + 255) / 256), 256, 0, stream>>>(x, xs, idx, W, bias, out);
        return;
    }

    short* xb = (short*)d_ws;

    cvt_x<<<2048, 256, 0, stream>>>(x, xb);
    // 1024 blocks x 512 thr; block = 32 m, wave = 4 m
    fused_gconv<<<(B_ * M_) / 32, 512, 0, stream>>>(xb, xs, idx, W, bias, out);
}

// Round 18
// 28.815 us; speedup vs baseline: 1.1728x; 1.1728x over previous
//
#include <hip/hip_runtime.h>
#include <math.h>

#define B_ 4
#define N_ 32768
#define M_ 8192
#define K_ 16
#define D_ 64
#define O_ 64

typedef __attribute__((ext_vector_type(8))) short bf16x8;
typedef __attribute__((ext_vector_type(4))) float f32x4;

// float -> bf16 bits, round-to-nearest-even (inputs are finite normals)
static __device__ __forceinline__ short f2bf(float f) {
    unsigned u = __float_as_uint(f);
    u += 0x7fffu + ((u >> 16) & 1u);
    return (short)(u >> 16);
}

// 8 consecutive floats -> bf16x8 (one MFMA k-chunk)
static __device__ __forceinline__ bf16x8 ld_bf8(const float* p) {
    float4 f0 = *(const float4*)p;
    float4 f1 = *(const float4*)(p + 4);
    bf16x8 v;
    v[0] = f2bf(f0.x); v[1] = f2bf(f0.y); v[2] = f2bf(f0.z); v[3] = f2bf(f0.w);
    v[4] = f2bf(f1.x); v[5] = f2bf(f1.y); v[6] = f2bf(f1.z); v[7] = f2bf(f1.w);
    return v;
}

// ---------------------------------------------------------------------------
// FINAL (R18 = revert to R11, the measured best at 28.9 us):
//   out[b,o,m] = relu( max_k (x[b,idx[m,k]].W1[o]) + xs[b,m].(W2-W1)[o] + b[o] )
// Session conclusion: across R8-R17 (split vs fused, fp32 vs bf16 gathers,
// 2/4/8 waves/SIMD, ILP pins, asm vmcnt pipelines, XCD/L2 affinity) every
// design converges to ~29-34 us, dominated by ~20-25 us of 2M-row scattered
// gathers — pinned by scattered-transaction throughput, insensitive to bytes
// (128B vs 256B rows), occupancy, and issue discipline. Streaming floor of
// the algebraic reformulation (~8 us) is unreachable without removing the
// gather itself. R11 structure: 512 blocks x 4 waves, wave = 16 m; idx
// hoisted to VGPRs (no DS read on the gather-issue path); W frags staged via
// LDS once (wave wv converts o-tile wv); deferred owner-lane accumulate;
// LDS-transposed coalesced stores.
// ---------------------------------------------------------------------------
__global__ __launch_bounds__(256)
void fused_gconv(const float* __restrict__ x, const float* __restrict__ xs,
                 const int* __restrict__ idx, const float* __restrict__ W,
                 const float* __restrict__ bias, float* __restrict__ out) {
    __shared__ int    ldsI[64 * 16];         // 4 KB: 64 m x 16 k
    __shared__ bf16x8 ldsW[4][2][2][64];     // 16 KB: [t][s][b1/bd][lane]
    __shared__ float  ldsB[64];
    __shared__ float  ldsT[64 * 65];         // transpose, stride 65

    const int tid  = threadIdx.x;
    const int blk  = blockIdx.x;       // 0..511
    const int bb   = blk >> 7;         // batch
    const int mblk = (blk & 127) * 64; // batch-local m base of block

    // stage idx: 4KB, fully coalesced (256 thr x int4)
    *(int4*)&ldsI[tid * 4] =
        *(const int4*)(idx + ((size_t)bb * M_ + mblk) * 16 + tid * 4);

    const int l  = tid & 63;
    const int wv = tid >> 6;           // wave id -> 16-m group, and W t-slice
    const int lr = l & 15;             // fragment row / col
    const int kg = l >> 4;             // k-group
    const int mw = wv * 16;            // group base within block

    // ---- W-frag stage: wave wv converts o-tile t=wv (b1 = W1, bd = W2-W1)
    {
        const int t = wv;
        #pragma unroll
        for (int s = 0; s < 2; ++s) {
            const float* wp = W + (size_t)(t * 16 + lr) * 128 + s * 32 + kg * 8;
            float4 f0 = *(const float4*)wp;
            float4 f1 = *(const float4*)(wp + 4);
            float4 g0 = *(const float4*)(wp + 64);
            float4 g1 = *(const float4*)(wp + 68);
            bf16x8 v1, vd;
            v1[0] = f2bf(f0.x); v1[1] = f2bf(f0.y); v1[2] = f2bf(f0.z); v1[3] = f2bf(f0.w);
            v1[4] = f2bf(f1.x); v1[5] = f2bf(f1.y); v1[6] = f2bf(f1.z); v1[7] = f2bf(f1.w);
            vd[0] = f2bf(g0.x - f0.x); vd[1] = f2bf(g0.y - f0.y);
            vd[2] = f2bf(g0.z - f0.z); vd[3] = f2bf(g0.w - f0.w);
            vd[4] = f2bf(g1.x - f1.x); vd[5] = f2bf(g1.y - f1.y);
            vd[6] = f2bf(g1.z - f1.z); vd[7] = f2bf(g1.w - f1.w);
            ldsW[t][s][0][l] = v1;
            ldsW[t][s][1][l] = vd;
        }
        if (tid < 64) ldsB[tid] = bias[tid];
    }
    __syncthreads();

    // read back full frag set (256B/thread from LDS) + bias
    bf16x8 b1[2][4], bd[2][4];
    float  binit[4];
    #pragma unroll
    for (int t = 0; t < 4; ++t) {
        #pragma unroll
        for (int s = 0; s < 2; ++s) {
            b1[s][t] = ldsW[t][s][0][l];
            bd[s][t] = ldsW[t][s][1][l];
        }
        binit[t] = ldsB[t * 16 + lr];
    }

    // center: wave's 16 xs rows vs (W2-W1), bias-init.
    const float* xsp = xs + ((size_t)bb * M_ + mblk + mw + lr) * 64 + kg * 8;
    bf16x8 axs0 = ld_bf8(xsp);
    bf16x8 axs1 = ld_bf8(xsp + 32);

    float vout[4][4];                  // [t][r]: o = t*16+lr, m = mw+kg*4+r
    #pragma unroll
    for (int t = 0; t < 4; ++t) {
        f32x4 a = {binit[t], binit[t], binit[t], binit[t]};
        a = __builtin_amdgcn_mfma_f32_16x16x32_bf16(axs0, bd[0][t], a, 0, 0, 0);
        a = __builtin_amdgcn_mfma_f32_16x16x32_bf16(axs1, bd[1][t], a, 0, 0, 0);
        vout[t][0] = a[0]; vout[t][1] = a[1];
        vout[t][2] = a[2]; vout[t][3] = a[3];
    }

    // ---- hoist ALL idx values to VGPRs (single lgkm wait; no DS read
    // remains on the gather-issue path inside the m-loop)
    int rr[16];
    #pragma unroll
    for (int m = 0; m < 16; ++m)
        rr[m] = ldsI[(mw + m) * 16 + lr];

    const float* xb = x + (size_t)bb * N_ * 64;

    // per-m: gather A-frag, 8 MFMAs, row-max (in-lane + 2 shfl), owner add.
    #pragma unroll
    for (int m = 0; m < 16; ++m) {
        const float* xp = xb + (size_t)(unsigned)rr[m] * 64 + kg * 8;
        bf16x8 a0 = ld_bf8(xp);
        bf16x8 a1 = ld_bf8(xp + 32);
        #pragma unroll
        for (int t = 0; t < 4; ++t) {
            f32x4 a = {0.f, 0.f, 0.f, 0.f};
            a = __builtin_amdgcn_mfma_f32_16x16x32_bf16(a0, b1[0][t], a, 0, 0, 0);
            a = __builtin_amdgcn_mfma_f32_16x16x32_bf16(a1, b1[1][t], a, 0, 0, 0);
            float v = fmaxf(fmaxf(a[0], a[1]), fmaxf(a[2], a[3]));
            v = fmaxf(v, __shfl_xor(v, 16));
            v = fmaxf(v, __shfl_xor(v, 32));           // max over 16 k-rows
            if ((m >> 2) == kg)                        // owner lane-group
                vout[t][m & 3] += v;
        }
    }

    // relu + LDS transpose write: [o = t*16+lr][m = mw + kg*4 + r]
    #pragma unroll
    for (int t = 0; t < 4; ++t)
        #pragma unroll
        for (int r = 0; r < 4; ++r) {
            float v = vout[t][r];
            ldsT[(t * 16 + lr) * 65 + mw + kg * 4 + r] = v > 0.f ? v : 0.f;
        }
    __syncthreads();

    // coalesced stores: thread tid -> o = tid>>2, 16 m at (tid&3)*16
    const int o  = tid >> 2;
    const int ms = (tid & 3) * 16;
    float* op = out + ((size_t)bb * 64 + o) * M_ + mblk + ms;
    #pragma unroll
    for (int j = 0; j < 4; ++j) {
        const float* lp = &ldsT[o * 65 + ms + j * 4];
        *(float4*)(op + j * 4) = make_float4(lp[0], lp[1], lp[2], lp[3]);
    }
}

extern "C" void kernel_launch(void* const* d_in, const int* in_sizes, int n_in,
                              void* d_out, int out_size, void* d_ws, size_t ws_size,
                              hipStream_t stream) {
    const float* x    = (const float*)d_in[0];
    const float* xs   = (const float*)d_in[1];
    const int*   idx  = (const int*)d_in[2];
    const float* W    = (const float*)d_in[3];
    const float* bias = (const float*)d_in[4];
    float* out = (float*)d_out;

    // 512 blocks x 256 thr; block = 64 m, wave = 16 m
    fused_gconv<<<(B_ * M_) / 64, 256, 0, stream>>>(x, xs, idx, W, bias, out);
}